// Round 4
// baseline (1029.702 us; speedup 1.0000x reference)
//
#include <hip/hip_runtime.h>
#include <hip/hip_bf16.h>
#include <math.h>

// ---------------------------------------------------------------------------
// 5x conv4d(valid)+relu -> flatten -> dense(1280->33)+relu -> dense(33->2)
// -> softmax.  B=256.
//
// R4 (re-bench x3): co-merged conv threads for conv1-3 + scalar (SMEM)
// weights.
//  - conv1-3 ("cm" template): thread = (ox,oy) line, accumulates ALL COUT
//    channels. Row LDS reads amortize xCOUT; weight addresses are
//    wave-uniform -> s_load (off the LDS pipe). Weights pre-packed to f16
//    global by pack_weights (layout [ci][kw][kx][ky][co][4], kz padded).
//  - conv4/5 keep the R3 path (per-(co,ox,oy) lines, LDS weights): their
//    (ox,oy) counts are too small to co-merge, and they are 6% of MACs.
//  - LDS slab per (b,ow) block, f16, z-stride ZP=24 (48B rows: bank group
//    12r mod 32 cycles all 8 groups -> conflict-free 8-row windows).
//  - kz pairs via v_dot2_f32_f16; odd-parity pairs via v_perm_b32.
// ---------------------------------------------------------------------------

#define BATCH 256
typedef _Float16 half_t;
typedef _Float16 h2_t __attribute__((ext_vector_type(2)));
typedef unsigned int uint32;

__device__ __forceinline__ float dot2f(uint32 a, uint32 b, float c) {
    return __builtin_amdgcn_fdot2(__builtin_bit_cast(h2_t, a),
                                  __builtin_bit_cast(h2_t, b), c, false);
}

// ---- weight pre-pack: fp32 global -> f16 global, [ci][kw][kx][ky][co][KP=4]
template <int CIN, int COUT, int K>
__device__ void pack_one(const float* __restrict__ w, half_t* __restrict__ wq,
                         int tid, int nt) {
    constexpr int KP = 4;
    constexpr int WTOT = CIN * K * K * K * COUT * KP;
    for (int t = tid; t < WTOT; t += nt) {
        const int kz = t % KP; int c = t / KP;
        const int co = c % COUT; c /= COUT;
        const int ky = c % K; c /= K;
        const int kx = c % K; c /= K;
        const int kw = c % K; const int ci = c / K;
        const float v = (kz < K)
            ? w[((((co * CIN + ci) * K + kw) * K + kx) * K + ky) * K + kz]
            : 0.0f;
        wq[t] = (half_t)v;
    }
}

__global__ void pack_weights(const float* __restrict__ w1,
                             const float* __restrict__ w2,
                             const float* __restrict__ w3,
                             half_t* __restrict__ q1,
                             half_t* __restrict__ q2,
                             half_t* __restrict__ q3) {
    pack_one<1, 3, 4>(w1, q1, threadIdx.x, blockDim.x);
    pack_one<3, 3, 4>(w2, q2, threadIdx.x, blockDim.x);
    pack_one<3, 4, 4>(w3, q3, threadIdx.x, blockDim.x);
}

// ---------------------------------------------------------------------------
// Co-merged conv: thread = (ox,oy), acc[COUT][OSZ]. Weights from f16 global
// at wave-uniform addresses (s_load). Used for conv1-3.
// ---------------------------------------------------------------------------
template <int CIN, int COUT, int K, int ISZ, int OSZ,
          int IPG, int OPG, int ZP, int NT, bool INF32>
__global__ __launch_bounds__(NT)
void conv4d_relu_cm(const void* __restrict__ in_v,
                    const half_t* __restrict__ wq,
                    const float* __restrict__ bias,
                    half_t* __restrict__ out) {
    constexpr int KP  = 4;                    // padded kz extent
    constexpr int R2  = ISZ * ISZ;
    constexpr int LINES = OSZ * OSZ;          // (ox,oy) lines per slab
    constexpr int RL  = OSZ + KP - 1;         // row halfs consumed
    constexpr int RQ  = (RL + 7) / 8;         // uint4 (8 f16) loads per row
    constexpr int NW  = RQ * 4;               // 32-bit words per row
    constexpr int NODD = (OSZ + 2) / 2;       // odd-parity pairs needed

    static_assert(NT >= LINES, "one compute pass requires NT >= LINES");
    static_assert(8 * RQ <= ZP, "row read overruns z-pad");
    static_assert(NODD + 1 <= NW, "perm source word out of range");

    __shared__ half_t slab[CIN * R2 * ZP];

    const int tid = threadIdx.x;
    const int b   = blockIdx.x / OSZ;
    const int ow  = blockIdx.x % OSZ;
    const int ox  = tid / OSZ;
    const int oy  = tid % OSZ;

    float acc[COUT][OSZ];
    #pragma unroll
    for (int co = 0; co < COUT; ++co) {
        const float bv = bias[co];
        #pragma unroll
        for (int oz = 0; oz < OSZ; ++oz) acc[co][oz] = bv;
    }

    for (int kw = 0; kw < K; ++kw) {
        __syncthreads();                      // readers of previous slab done
        const int iw = ow + kw;
        if constexpr (INF32) {
            // conv1: fp32 natural layout, CIN==1; float2 -> h2 packed stores
            const float* g = (const float*)in_v +
                ((size_t)b * ISZ + iw) * (size_t)(R2 * ISZ);
            for (int t = tid; t < (R2 * ISZ) / 2; t += NT) {
                const float2 v = ((const float2*)g)[t];
                const int e = 2 * t;
                const int r = e / ISZ, z = e % ISZ;   // ISZ even: no row split
                h2_t pv = { (half_t)v.x, (half_t)v.y };
                *(uint32*)&slab[r * ZP + z] = __builtin_bit_cast(uint32, pv);
            }
        } else {
            constexpr int CPR = IPG / 8;      // uint4 chunks per row
            constexpr int NCH = CIN * R2 * CPR;
            const half_t* inp = (const half_t*)in_v;
            for (int t = tid; t < NCH; t += NT) {
                const int ci  = t / (R2 * CPR);
                const int rem = t % (R2 * CPR);
                const int r = rem / CPR, c = rem % CPR;
                const uint4* g = (const uint4*)(inp +
                    ((size_t)(b * CIN + ci) * ISZ + iw) * (size_t)(R2 * IPG));
                const uint4 v = g[rem];       // == (r*IPG + 8c)/8
                *(uint4*)&slab[(ci * R2 + r) * ZP + 8 * c] = v;
            }
        }
        __syncthreads();

        if (tid < LINES) {
            #pragma unroll 1
            for (int ci = 0; ci < CIN; ++ci) {
                #pragma unroll 1
                for (int kx = 0; kx < K; ++kx) {
                    #pragma unroll
                    for (int ky = 0; ky < K; ++ky) {
                        const half_t* rp =
                            &slab[((ci * ISZ + ox + kx) * ISZ + oy + ky) * ZP];
                        uint32 wd[NW];
                        #pragma unroll
                        for (int q = 0; q < RQ; ++q) {
                            const uint4 v = ((const uint4*)rp)[q];
                            wd[4*q+0] = v.x; wd[4*q+1] = v.y;
                            wd[4*q+2] = v.z; wd[4*q+3] = v.w;
                        }
                        uint32 od[NODD];
                        #pragma unroll
                        for (int i = 0; i < NODD; ++i)
                            od[i] = __builtin_amdgcn_perm(wd[i + 1], wd[i],
                                                          0x05040302u);
                        // wave-uniform weight base -> scalar loads
                        const half_t* wp = wq +
                            ((((ci * K + kw) * K + kx) * K + ky) * COUT) * KP;
                        #pragma unroll
                        for (int co = 0; co < COUT; ++co) {
                            const uint2 wv = *(const uint2*)&wp[co * KP];
                            #pragma unroll
                            for (int oz = 0; oz < OSZ; ++oz) {
                                const int s1 = oz + 2;
                                const uint32 p0 = (oz & 1) ? od[oz >> 1]
                                                           : wd[oz >> 1];
                                const uint32 p1 = (s1 & 1) ? od[s1 >> 1]
                                                           : wd[s1 >> 1];
                                acc[co][oz] = dot2f(p0, wv.x,
                                               dot2f(p1, wv.y, acc[co][oz]));
                            }
                        }
                    }
                }
            }
        }
    }

    // ---- epilogue: relu, pack, store to [b][co][ow][ox][oy][OPG]
    if (tid < LINES) {
        #pragma unroll
        for (int co = 0; co < COUT; ++co) {
            half_t* op = out +
                (((((size_t)b * COUT + co) * OSZ + ow) * OSZ + ox) * OSZ + oy)
                * OPG;
            #pragma unroll
            for (int p = 0; p < OSZ / 2; ++p) {
                h2_t pv = { (half_t)fmaxf(acc[co][2*p],     0.0f),
                            (half_t)fmaxf(acc[co][2*p + 1], 0.0f) };
                ((uint32*)op)[p] = __builtin_bit_cast(uint32, pv);
            }
            if constexpr (OSZ & 1)
                op[OSZ - 1] = (half_t)fmaxf(acc[co][OSZ - 1], 0.0f);
        }
    }
}

// ---------------------------------------------------------------------------
// R3 conv path (per-(co,ox,oy) lines, LDS weights) — kept for conv4/conv5.
// ---------------------------------------------------------------------------
template <int CIN, int COUT, int K, int ISZ, int OSZ,
          int IPG, int OPG, int ZP, int NT, bool INF32>
__global__ __launch_bounds__(NT)
void conv4d_relu_f16(const void* __restrict__ in_v,
                     const float* __restrict__ w,
                     const float* __restrict__ bias,
                     half_t* __restrict__ out) {
    constexpr int KP  = 4;
    constexpr int R2  = ISZ * ISZ;
    constexpr int WTOT = CIN * K * K * K * COUT * KP;
    constexpr int LINES = COUT * OSZ * OSZ;
    constexpr int NIT = (LINES + NT - 1) / NT;
    constexpr int RL  = OSZ + KP - 1;
    constexpr int RQ  = (RL + 7) / 8;
    constexpr int NW  = RQ * 4;
    constexpr int NODD = (OSZ + 2) / 2;

    static_assert(8 * RQ <= ZP, "row read overruns z-pad");
    static_assert(NODD + 1 <= NW, "perm source word out of range");

    __shared__ half_t sw[WTOT];
    __shared__ half_t slab[CIN * R2 * ZP];

    const int tid = threadIdx.x;
    const int b   = blockIdx.x / OSZ;
    const int ow  = blockIdx.x % OSZ;

    for (int t = tid; t < WTOT; t += NT) {
        const int kz = t % KP; int c = t / KP;
        const int co = c % COUT; c /= COUT;
        const int ky = c % K; c /= K;
        const int kx = c % K; c /= K;
        const int kw = c % K; const int ci = c / K;
        const float v = (kz < K)
            ? w[((((co * CIN + ci) * K + kw) * K + kx) * K + ky) * K + kz]
            : 0.0f;
        sw[t] = (half_t)v;
    }

    float acc[NIT][OSZ];
    #pragma unroll
    for (int it = 0; it < NIT; ++it) {
        const int line = tid + it * NT;
        const float bv = (line < LINES) ? bias[line % COUT] : 0.0f;
        #pragma unroll
        for (int oz = 0; oz < OSZ; ++oz) acc[it][oz] = bv;
    }

    for (int kw = 0; kw < K; ++kw) {
        __syncthreads();
        const int iw = ow + kw;
        if constexpr (INF32) {
            const float* g = (const float*)in_v + ((size_t)b * ISZ + iw) * (size_t)(R2 * ISZ);
            for (int t = tid; t < R2 * ISZ; t += NT) {
                const int r = t / ISZ, z = t % ISZ;
                slab[r * ZP + z] = (half_t)g[t];
            }
        } else {
            constexpr int CPR = IPG / 8;
            constexpr int NCH = CIN * R2 * CPR;
            const half_t* inp = (const half_t*)in_v;
            for (int t = tid; t < NCH; t += NT) {
                const int ci  = t / (R2 * CPR);
                const int rem = t % (R2 * CPR);
                const int r = rem / CPR, c = rem % CPR;
                const uint4* g = (const uint4*)(inp +
                    ((size_t)(b * CIN + ci) * ISZ + iw) * (size_t)(R2 * IPG));
                const uint4 v = g[rem];
                *(uint4*)&slab[(ci * R2 + r) * ZP + 8 * c] = v;
            }
        }
        __syncthreads();

        #pragma unroll
        for (int it = 0; it < NIT; ++it) {
            const int line = tid + it * NT;
            if (line >= LINES) continue;
            const int co = line % COUT;
            const int xy = line / COUT;
            const int ox = xy / OSZ;
            const int oy = xy % OSZ;
            #pragma unroll 1
            for (int ci = 0; ci < CIN; ++ci) {
                #pragma unroll 1
                for (int kx = 0; kx < K; ++kx) {
                    #pragma unroll
                    for (int ky = 0; ky < K; ++ky) {
                        const half_t* rp = &slab[((ci * ISZ + ox + kx) * ISZ + oy + ky) * ZP];
                        uint32 wd[NW];
                        #pragma unroll
                        for (int q = 0; q < RQ; ++q) {
                            const uint4 v = ((const uint4*)rp)[q];
                            wd[4*q+0] = v.x; wd[4*q+1] = v.y;
                            wd[4*q+2] = v.z; wd[4*q+3] = v.w;
                        }
                        uint32 od[NODD];
                        #pragma unroll
                        for (int i = 0; i < NODD; ++i)
                            od[i] = __builtin_amdgcn_perm(wd[i + 1], wd[i], 0x05040302u);
                        const int wb = ((((ci * K + kw) * K + kx) * K + ky) * COUT + co) * KP;
                        const uint2 wv = *(const uint2*)&sw[wb];
                        #pragma unroll
                        for (int oz = 0; oz < OSZ; ++oz) {
                            const int s1 = oz + 2;
                            const uint32 p0 = (oz & 1) ? od[oz >> 1] : wd[oz >> 1];
                            const uint32 p1 = (s1 & 1) ? od[s1 >> 1] : wd[s1 >> 1];
                            acc[it][oz] = dot2f(p0, wv.x, dot2f(p1, wv.y, acc[it][oz]));
                        }
                    }
                }
            }
        }
    }

    #pragma unroll
    for (int it = 0; it < NIT; ++it) {
        const int line = tid + it * NT;
        if (line >= LINES) continue;
        const int co = line % COUT;
        const int xy = line / COUT;
        const int ox = xy / OSZ;
        const int oy = xy % OSZ;
        half_t* op = out + (((((size_t)b * COUT + co) * OSZ + ow) * OSZ + ox) * OSZ + oy) * OPG;
        #pragma unroll
        for (int p = 0; p < OSZ / 2; ++p) {
            h2_t pv = { (half_t)fmaxf(acc[it][2*p],     0.0f),
                        (half_t)fmaxf(acc[it][2*p + 1], 0.0f) };
            ((uint32*)op)[p] = __builtin_bit_cast(uint32, pv);
        }
        if constexpr (OSZ & 1)
            op[OSZ - 1] = (half_t)fmaxf(acc[it][OSZ - 1], 0.0f);
    }
}

// dense1: out[b,j] = relu(sum_k h[b,k]*w[j,k] + bias[j]); h f16 [256,1280]
__global__ void dense1_relu_f16(const half_t* __restrict__ h,
                                const float* __restrict__ w,
                                const float* __restrict__ bias,
                                float* __restrict__ out) {
    int idx = blockIdx.x * blockDim.x + threadIdx.x;
    if (idx >= BATCH * 33) return;
    const int j = idx % 33;
    const int i = idx / 33;
    const half_t* hr = h + (size_t)i * 1280;
    const float*  wr = w + (size_t)j * 1280;
    float a0 = bias[j], a1 = 0.f, a2 = 0.f, a3 = 0.f;
    for (int k = 0; k < 1280; k += 4) {
        a0 = fmaf((float)hr[k + 0], wr[k + 0], a0);
        a1 = fmaf((float)hr[k + 1], wr[k + 1], a1);
        a2 = fmaf((float)hr[k + 2], wr[k + 2], a2);
        a3 = fmaf((float)hr[k + 3], wr[k + 3], a3);
    }
    out[idx] = fmaxf((a0 + a1) + (a2 + a3), 0.0f);
}

// dense2 + softmax over 2 classes. h:[256,33] fp32, w:[2,33], out:[256,2]
__global__ void dense2_softmax(const float* __restrict__ h,
                               const float* __restrict__ w,
                               const float* __restrict__ bias,
                               float* __restrict__ out) {
    int i = blockIdx.x * blockDim.x + threadIdx.x;
    if (i >= BATCH) return;
    const float* hr = h + (size_t)i * 33;
    float a0 = bias[0], a1 = bias[1];
    for (int k = 0; k < 33; ++k) {
        a0 = fmaf(hr[k], w[k], a0);
        a1 = fmaf(hr[k], w[33 + k], a1);
    }
    const float m = fmaxf(a0, a1);
    const float e0 = expf(a0 - m);
    const float e1 = expf(a1 - m);
    const float s = e0 + e1;
    out[i * 2 + 0] = e0 / s;
    out[i * 2 + 1] = e1 / s;
}

extern "C" void kernel_launch(void* const* d_in, const int* in_sizes, int n_in,
                              void* d_out, int out_size, void* d_ws, size_t ws_size,
                              hipStream_t stream) {
    const float* x   = (const float*)d_in[0];
    const float* w1  = (const float*)d_in[1];
    const float* b1  = (const float*)d_in[2];
    const float* w2  = (const float*)d_in[3];
    const float* b2  = (const float*)d_in[4];
    const float* w3  = (const float*)d_in[5];
    const float* b3  = (const float*)d_in[6];
    const float* w4  = (const float*)d_in[7];
    const float* b4  = (const float*)d_in[8];
    const float* w5  = (const float*)d_in[9];
    const float* b5  = (const float*)d_in[10];
    const float* dw1 = (const float*)d_in[11];
    const float* db1 = (const float*)d_in[12];
    const float* dw2 = (const float*)d_in[13];
    const float* db2 = (const float*)d_in[14];

    // Workspace (f16 units). Region A at 0, region B at 42M f16 (84 MB).
    //  A: h1 [256][3][15][15][15][16] = 41.472M f16  / h3 / h5
    //     + packed f16 weights q1..q3 at A+41.6M (14K f16, above h1 end)
    //  B: h2 [256][3][12][12][12][16] = 21.23M f16  / h4 / h6(fp32, +8M)
    half_t* wsA = (half_t*)d_ws;
    half_t* wsB = wsA + 42000000;

    half_t* h1 = wsA;                 // padded z=16
    half_t* h2 = wsB;                 // padded z=16
    half_t* h3 = wsA;                 // padded z=16
    half_t* h4 = wsB;                 // padded z=8
    half_t* h5 = wsA;                 // natural [256][1280]
    float*  h6 = (float*)(wsB + 8000000);
    half_t* q1 = wsA + 41600000;      // 1*64*3*4 = 768 f16
    half_t* q2 = q1 + 768;            // 3*64*3*4 = 2304 f16
    half_t* q3 = q2 + 2304;           // 3*64*4*4 = 3072 f16
    float* outp = (float*)d_out;

    // weight pre-pack for conv1-3 (tiny; stream-ordered before convs)
    hipLaunchKernelGGL(pack_weights, dim3(1), dim3(256), 0, stream,
                       w1, w2, w3, q1, q2, q3);

    // conv1: in fp32 natural -> h1;  blocks (b,ow)=3840, 225 lines/block
    hipLaunchKernelGGL((conv4d_relu_cm<1, 3, 4, 18, 15, 8, 16, 24, 256, true>),
                       dim3(BATCH * 15), dim3(256), 0, stream, x, q1, b1, h1);
    // conv2: h1 -> h2;  3072 blocks, 144 lines/block
    hipLaunchKernelGGL((conv4d_relu_cm<3, 3, 4, 15, 12, 16, 16, 24, 192, false>),
                       dim3(BATCH * 12), dim3(192), 0, stream, h1, q2, b2, h2);
    // conv3: h2 -> h3;  2304 blocks, 81 lines/block
    hipLaunchKernelGGL((conv4d_relu_cm<3, 4, 4, 12, 9, 16, 16, 24, 128, false>),
                       dim3(BATCH * 9), dim3(128), 0, stream, h2, q3, b3, h3);
    // conv4: h3 -> h4;  1536 blocks (R3 path)
    hipLaunchKernelGGL((conv4d_relu_f16<4, 5, 4, 9, 6, 16, 8, 24, 192, false>),
                       dim3(BATCH * 6), dim3(192), 0, stream, h3, w4, b4, h4);
    // conv5: h4 -> h5 (natural, z=4);  1024 blocks (R3 path)
    hipLaunchKernelGGL((conv4d_relu_f16<5, 5, 3, 6, 4, 8, 4, 8, 128, false>),
                       dim3(BATCH * 4), dim3(128), 0, stream, h4, w5, b5, h5);
    {   // dense1
        dim3 grid((BATCH * 33 + 255) / 256);
        hipLaunchKernelGGL(dense1_relu_f16, grid, dim3(256), 0, stream, h5, dw1, db1, h6);
    }
    {   // dense2 + softmax
        hipLaunchKernelGGL(dense2_softmax, dim3(1), dim3(256), 0, stream,
                           h6, dw2, db2, outp);
    }
}